// Round 4
// baseline (578.911 us; speedup 1.0000x reference)
//
#include <hip/hip_runtime.h>
#include <hip/hip_cooperative_groups.h>
#include <math.h>

namespace cg = cooperative_groups;

#define NB 16
#define PP 1024
#define DD 64
#define MAX_ITER 10
#define RCH 16                 // rows per coop block
#define NCH (PP / RCH)         // 64 row-chunks per batch
#define NBLK (NB * NCH)        // 1024 coop blocks
#define RCHUNK 16              // fallback: rows per v-partial block
#define NCHUNK (PP / RCHUNK)

constexpr float EPSV    = 0.1f;
constexpr float INV_EPS = 10.0f;
constexpr float LOG2E   = 1.44269504088896340736f;
constexpr float LOG_MU  = -6.93146156597137f;   // log(1/1024 + 1e-8)
constexpr float THRESHV = 0.1f;

// ===========================================================================
// PATH A: persistent cooperative kernel, C resident in registers.
// Block = (batch n, 16-row chunk rc); acc[16][4] per thread = the 16x1024 slab.
// 2 grid syncs per iteration. All reductions fixed-order -> deterministic.
// ===========================================================================
__global__ __launch_bounds__(256, 4) void sinkhorn_fused(
    const float* __restrict__ x, const float* __restrict__ y,
    float* __restrict__ pi, float* __restrict__ pm, float* __restrict__ ps,
    float* __restrict__ bg, float* __restrict__ errBlk, int* __restrict__ doneF)
{
  cg::grid_group grid = cg::this_grid();
  const int bid  = blockIdx.x;
  const int n    = bid >> 6;
  const int rc   = bid & (NCH - 1);
  const int tid  = threadIdx.x;
  const int lane = tid & 63;
  const int wv   = tid >> 6;
  const int c0   = tid * 4;

  __shared__ float xs[RCH][68];
  __shared__ float aArr[RCH];
  __shared__ float redm[RCH][4];
  __shared__ float reds[RCH][4];
  __shared__ float dsum[RCH];

  const float* xb = x + ((size_t)n * PP + rc * RCH) * DD;
  for (int t = tid; t < RCH * 16; t += 256) {
    int r = t >> 4, d4 = (t & 15) * 4;
    float4 v = *(const float4*)(xb + r * DD + d4);
    xs[r][d4] = v.x; xs[r][d4 + 1] = v.y; xs[r][d4 + 2] = v.z; xs[r][d4 + 3] = v.w;
  }
  if (tid < RCH) aArr[tid] = 0.f;
  __syncthreads();

  float acc[RCH][4];
  #pragma unroll
  for (int r = 0; r < RCH; ++r) { acc[r][0] = 0.f; acc[r][1] = 0.f; acc[r][2] = 0.f; acc[r][3] = 0.f; }

  const float* yb = y + ((size_t)n * PP + c0) * DD;
  for (int d0 = 0; d0 < DD; d0 += 4) {
    float4 y0 = *(const float4*)(yb + d0);
    float4 y1 = *(const float4*)(yb + DD + d0);
    float4 y2 = *(const float4*)(yb + 2 * DD + d0);
    float4 y3 = *(const float4*)(yb + 3 * DD + d0);
    #pragma unroll
    for (int r = 0; r < RCH; ++r) {
      float4 xv = *(const float4*)&xs[r][d0];
      float d;
      d = xv.x - y0.x; acc[r][0] = fmaf(d, d, acc[r][0]);
      d = xv.y - y0.y; acc[r][0] = fmaf(d, d, acc[r][0]);
      d = xv.z - y0.z; acc[r][0] = fmaf(d, d, acc[r][0]);
      d = xv.w - y0.w; acc[r][0] = fmaf(d, d, acc[r][0]);
      d = xv.x - y1.x; acc[r][1] = fmaf(d, d, acc[r][1]);
      d = xv.y - y1.y; acc[r][1] = fmaf(d, d, acc[r][1]);
      d = xv.z - y1.z; acc[r][1] = fmaf(d, d, acc[r][1]);
      d = xv.w - y1.w; acc[r][1] = fmaf(d, d, acc[r][1]);
      d = xv.x - y2.x; acc[r][2] = fmaf(d, d, acc[r][2]);
      d = xv.y - y2.y; acc[r][2] = fmaf(d, d, acc[r][2]);
      d = xv.z - y2.z; acc[r][2] = fmaf(d, d, acc[r][2]);
      d = xv.w - y2.w; acc[r][2] = fmaf(d, d, acc[r][2]);
      d = xv.x - y3.x; acc[r][3] = fmaf(d, d, acc[r][3]);
      d = xv.y - y3.y; acc[r][3] = fmaf(d, d, acc[r][3]);
      d = xv.z - y3.z; acc[r][3] = fmaf(d, d, acc[r][3]);
      d = xv.w - y3.w; acc[r][3] = fmaf(d, d, acc[r][3]);
    }
  }
  #pragma unroll
  for (int r = 0; r < RCH; ++r) {
    acc[r][0] *= INV_EPS; acc[r][1] *= INV_EPS; acc[r][2] *= INV_EPS; acc[r][3] *= INV_EPS;
  }

  float4 bv = make_float4(0.f, 0.f, 0.f, 0.f);
  int done = 0;

  for (int it = 0; it < MAX_ITER; ++it) {
    if (!done) {
      #pragma unroll
      for (int r = 0; r < RCH; ++r) {
        float m = fmaxf(fmaxf(bv.x - acc[r][0], bv.y - acc[r][1]),
                        fmaxf(bv.z - acc[r][2], bv.w - acc[r][3]));
        #pragma unroll
        for (int off = 32; off; off >>= 1) m = fmaxf(m, __shfl_xor(m, off));
        if (lane == r) redm[r][wv] = m;
      }
      __syncthreads();
      if (tid < RCH) {
        float m = fmaxf(fmaxf(redm[tid][0], redm[tid][1]), fmaxf(redm[tid][2], redm[tid][3]));
        redm[tid][0] = m;
      }
      __syncthreads();
      #pragma unroll
      for (int r = 0; r < RCH; ++r) {
        float M = redm[r][0];
        float s = exp2f((bv.x - acc[r][0] - M) * LOG2E)
                + exp2f((bv.y - acc[r][1] - M) * LOG2E)
                + exp2f((bv.z - acc[r][2] - M) * LOG2E)
                + exp2f((bv.w - acc[r][3] - M) * LOG2E);
        #pragma unroll
        for (int off = 32; off; off >>= 1) s += __shfl_xor(s, off);
        if (lane == r) reds[r][wv] = s;
      }
      __syncthreads();
      if (tid < RCH) {
        float s  = reds[tid][0] + reds[tid][1] + reds[tid][2] + reds[tid][3];
        float an = LOG_MU - (redm[tid][0] + logf(s));
        dsum[tid] = fabsf(an - aArr[tid]);
        aArr[tid] = an;
      }
      __syncthreads();
      if (tid == 0) {
        float e = 0.f;
        #pragma unroll
        for (int r = 0; r < RCH; ++r) e += dsum[r];
        errBlk[bid] = e;
      }
      float mc[4], sc[4];
      #pragma unroll
      for (int c = 0; c < 4; ++c) {
        float m = -INFINITY;
        #pragma unroll
        for (int r = 0; r < RCH; ++r) m = fmaxf(m, aArr[r] - acc[r][c]);
        float s = 0.f;
        #pragma unroll
        for (int r = 0; r < RCH; ++r) s += exp2f((aArr[r] - acc[r][c] - m) * LOG2E);
        mc[c] = m; sc[c] = s;
      }
      size_t off = ((size_t)(n * NCH + rc)) * PP + c0;
      *(float4*)(pm + off) = make_float4(mc[0], mc[1], mc[2], mc[3]);
      *(float4*)(ps + off) = make_float4(sc[0], sc[1], sc[2], sc[3]);
    }

    __threadfence();
    grid.sync();

    if (!done) {
      if (bid < 64) {
        const int cb = bid >> 2;
        const int j  = ((bid & 3) << 8) + tid;
        const float* pmn = pm + (size_t)cb * NCH * PP + j;
        const float* psn = ps + (size_t)cb * NCH * PP + j;
        float m = -INFINITY, s = 0.f;
        #pragma unroll 4
        for (int ch = 0; ch < NCH; ++ch) {
          float mcv = pmn[(size_t)ch * PP];
          float scv = psn[(size_t)ch * PP];
          float mn  = fmaxf(m, mcv);
          s = fmaf(s, exp2f((m - mn) * LOG2E), scv * exp2f((mcv - mn) * LOG2E));
          m = mn;
        }
        bg[cb * PP + j] = LOG_MU - (m + logf(s));
      } else if (bid == 64) {
        float e = 0.f;
        for (int t = tid; t < NBLK; t += 256) e += errBlk[t];
        #pragma unroll
        for (int off = 32; off; off >>= 1) e += __shfl_xor(e, off);
        if (lane == 0) reds[0][wv] = e;
        __syncthreads();
        if (tid == 0) {
          float tot = reds[0][0] + reds[0][1] + reds[0][2] + reds[0][3];
          doneF[it] = (tot * (EPSV / (float)NB) < THRESHV) ? 1 : 0;
        }
      }
    } else if (bid == 64 && tid == 0) {
      doneF[it] = 1;
    }

    __threadfence();
    grid.sync();
    __threadfence();

    done = doneF[it];
    if (!done) bv = *(const float4*)(bg + n * PP + c0);
  }

  float4 bf = *(const float4*)(bg + n * PP + c0);
  #pragma unroll
  for (int r = 0; r < RCH; ++r) {
    float ar = aArr[r];
    float4 o;
    o.x = exp2f((ar + bf.x - acc[r][0]) * LOG2E);
    o.y = exp2f((ar + bf.y - acc[r][1]) * LOG2E);
    o.z = exp2f((ar + bf.z - acc[r][2]) * LOG2E);
    o.w = exp2f((ar + bf.w - acc[r][3]) * LOG2E);
    *(float4*)(pi + ((size_t)(n * PP + rc * RCH + r)) * PP + c0) = o;
  }
}

// ===========================================================================
// PATH B (fallback, proven round-2 code): Cs in d_out, multi-kernel.
// ===========================================================================
__global__ __launch_bounds__(256) void compute_c(
    const float* __restrict__ x, const float* __restrict__ y,
    float* __restrict__ Cs, float* __restrict__ a, float* __restrict__ b,
    int* __restrict__ doneArr)
{
  const int bid = blockIdx.x;
  const int n   = bid >> 7;
  const int ib  = (bid >> 3) & 15;
  const int jb  = bid & 7;

  if (bid == 0) {
    for (int t = threadIdx.x; t < NB * PP; t += 256) { a[t] = 0.f; b[t] = 0.f; }
    if (threadIdx.x < 16) doneArr[threadIdx.x] = 0;
  }

  __shared__ float xs[64][68];
  __shared__ float ys[128][68];

  const float* xb = x + ((size_t)n * PP + ib * 64) * DD;
  const float* yb = y + ((size_t)n * PP + jb * 128) * DD;

  for (int t = threadIdx.x; t < 64 * 16; t += 256) {
    int r = t >> 4, d4 = (t & 15) * 4;
    float4 v = *(const float4*)(xb + r * DD + d4);
    xs[r][d4] = v.x; xs[r][d4 + 1] = v.y; xs[r][d4 + 2] = v.z; xs[r][d4 + 3] = v.w;
  }
  for (int t = threadIdx.x; t < 128 * 16; t += 256) {
    int r = t >> 4, d4 = (t & 15) * 4;
    float4 v = *(const float4*)(yb + (size_t)r * DD + d4);
    ys[r][d4] = v.x; ys[r][d4 + 1] = v.y; ys[r][d4 + 2] = v.z; ys[r][d4 + 3] = v.w;
  }
  __syncthreads();

  const int tx = threadIdx.x & 15;
  const int ty = threadIdx.x >> 4;
  const int i0 = ty * 4;

  float acc[4][8] = {};
  for (int d0 = 0; d0 < 64; d0 += 4) {
    float4 xv[4], yv[8];
    #pragma unroll
    for (int ii = 0; ii < 4; ++ii) xv[ii] = *(const float4*)&xs[i0 + ii][d0];
    #pragma unroll
    for (int jj = 0; jj < 8; ++jj) yv[jj] = *(const float4*)&ys[tx + 16 * jj][d0];
    #pragma unroll
    for (int ii = 0; ii < 4; ++ii) {
      #pragma unroll
      for (int jj = 0; jj < 8; ++jj) {
        float d;
        d = xv[ii].x - yv[jj].x; acc[ii][jj] = fmaf(d, d, acc[ii][jj]);
        d = xv[ii].y - yv[jj].y; acc[ii][jj] = fmaf(d, d, acc[ii][jj]);
        d = xv[ii].z - yv[jj].z; acc[ii][jj] = fmaf(d, d, acc[ii][jj]);
        d = xv[ii].w - yv[jj].w; acc[ii][jj] = fmaf(d, d, acc[ii][jj]);
      }
    }
  }

  float* outb = Cs + ((size_t)n * PP + ib * 64) * PP + jb * 128;
  #pragma unroll
  for (int ii = 0; ii < 4; ++ii)
    #pragma unroll
    for (int jj = 0; jj < 8; ++jj)
      outb[(size_t)(i0 + ii) * PP + tx + 16 * jj] = acc[ii][jj] * INV_EPS;
}

__global__ __launch_bounds__(256) void u_kernel(
    const float* __restrict__ Cs, float* __restrict__ a, const float* __restrict__ b,
    float* __restrict__ err_rows, const int* __restrict__ doneArr, int it)
{
  if (doneArr[it]) return;
  const int lane = threadIdx.x & 63;
  const int row  = (blockIdx.x << 2) + (threadIdx.x >> 6);
  const int n    = row >> 10;
  const float* crow = Cs + (size_t)row * PP;
  const float* bn   = b + n * PP;

  float vals[16];
  float m = -INFINITY;
  #pragma unroll
  for (int kk = 0; kk < 4; ++kk) {
    float4 c4 = *(const float4*)(crow + lane * 4 + kk * 256);
    float4 b4 = *(const float4*)(bn   + lane * 4 + kk * 256);
    float t0 = b4.x - c4.x, t1 = b4.y - c4.y, t2 = b4.z - c4.z, t3 = b4.w - c4.w;
    vals[4*kk+0] = t0; vals[4*kk+1] = t1; vals[4*kk+2] = t2; vals[4*kk+3] = t3;
    m = fmaxf(m, fmaxf(fmaxf(t0, t1), fmaxf(t2, t3)));
  }
  #pragma unroll
  for (int off = 32; off > 0; off >>= 1) m = fmaxf(m, __shfl_xor(m, off));
  float s = 0.f;
  #pragma unroll
  for (int t = 0; t < 16; ++t) s += exp2f((vals[t] - m) * LOG2E);
  #pragma unroll
  for (int off = 32; off > 0; off >>= 1) s += __shfl_xor(s, off);
  if (lane == 0) {
    float an = LOG_MU - (m + logf(s));
    float delta = fabsf(an - a[row]);
    a[row] = an;
    err_rows[row] = delta;
  }
}

__global__ __launch_bounds__(256) void v_partial(
    const float* __restrict__ Cs, const float* __restrict__ a,
    float* __restrict__ pm, float* __restrict__ ps,
    const int* __restrict__ doneArr, int it)
{
  if (doneArr[it]) return;
  const int n  = blockIdx.x >> 6;
  const int rc = blockIdx.x & (NCHUNK - 1);
  const int j0 = threadIdx.x * 4;
  const float* cb = Cs + ((size_t)n * PP + rc * RCHUNK) * PP + j0;
  const float* an = a + n * PP + rc * RCHUNK;

  float m0 = -INFINITY, m1 = -INFINITY, m2 = -INFINITY, m3 = -INFINITY;
  float s0 = 0.f, s1 = 0.f, s2 = 0.f, s3 = 0.f;
  #pragma unroll
  for (int r = 0; r < RCHUNK; ++r) {
    float ar = an[r];
    float4 c4 = *(const float4*)(cb + (size_t)r * PP);
    float t, mn;
    t = ar - c4.x; mn = fmaxf(m0, t); s0 = fmaf(s0, exp2f((m0-mn)*LOG2E), exp2f((t-mn)*LOG2E)); m0 = mn;
    t = ar - c4.y; mn = fmaxf(m1, t); s1 = fmaf(s1, exp2f((m1-mn)*LOG2E), exp2f((t-mn)*LOG2E)); m1 = mn;
    t = ar - c4.z; mn = fmaxf(m2, t); s2 = fmaf(s2, exp2f((m2-mn)*LOG2E), exp2f((t-mn)*LOG2E)); m2 = mn;
    t = ar - c4.w; mn = fmaxf(m3, t); s3 = fmaf(s3, exp2f((m3-mn)*LOG2E), exp2f((t-mn)*LOG2E)); m3 = mn;
  }
  size_t off = ((size_t)n * NCHUNK + rc) * PP + j0;
  *(float4*)(pm + off) = make_float4(m0, m1, m2, m3);
  *(float4*)(ps + off) = make_float4(s0, s1, s2, s3);
}

__global__ __launch_bounds__(256) void v_combine(
    const float* __restrict__ pm, const float* __restrict__ ps,
    float* __restrict__ b, const float* __restrict__ err_rows,
    int* __restrict__ doneArr, int it)
{
  if (doneArr[it]) {
    if (blockIdx.x == 0 && threadIdx.x == 0) doneArr[it + 1] = 1;
    return;
  }
  const int col = blockIdx.x * 256 + threadIdx.x;
  const int n = col >> 10, j = col & (PP - 1);
  const float* pmn = pm + (size_t)n * NCHUNK * PP + j;
  const float* psn = ps + (size_t)n * NCHUNK * PP + j;

  float m = -INFINITY, s = 0.f;
  #pragma unroll 8
  for (int c = 0; c < NCHUNK; ++c) {
    float mc = pmn[(size_t)c * PP];
    float sc = psn[(size_t)c * PP];
    float mn = fmaxf(m, mc);
    s = fmaf(s, exp2f((m - mn) * LOG2E), sc * exp2f((mc - mn) * LOG2E));
    m = mn;
  }
  b[col] = LOG_MU - (m + logf(s));

  if (blockIdx.x == 0) {
    __shared__ float red[4];
    float loc = 0.f;
    for (int t = threadIdx.x; t < NB * PP; t += 256) loc += err_rows[t];
    #pragma unroll
    for (int off = 32; off > 0; off >>= 1) loc += __shfl_xor(loc, off);
    if ((threadIdx.x & 63) == 0) red[threadIdx.x >> 6] = loc;
    __syncthreads();
    if (threadIdx.x == 0) {
      float tot = red[0] + red[1] + red[2] + red[3];
      float err = tot * (EPSV / (float)NB);
      doneArr[it + 1] = (err < THRESHV) ? 1 : 0;
    }
  }
}

__global__ __launch_bounds__(256) void pi_kernel(
    float* __restrict__ Cs, const float* __restrict__ a, const float* __restrict__ b)
{
  const int lane = threadIdx.x & 63;
  const int row  = (blockIdx.x << 2) + (threadIdx.x >> 6);
  const int n    = row >> 10;
  const float ai = a[row];
  float* crow = Cs + (size_t)row * PP;
  const float* bn = b + n * PP;
  #pragma unroll
  for (int kk = 0; kk < 4; ++kk) {
    float4 c4 = *(const float4*)(crow + lane * 4 + kk * 256);
    float4 b4 = *(const float4*)(bn   + lane * 4 + kk * 256);
    float4 r;
    r.x = exp2f((ai + b4.x - c4.x) * LOG2E);
    r.y = exp2f((ai + b4.y - c4.y) * LOG2E);
    r.z = exp2f((ai + b4.z - c4.z) * LOG2E);
    r.w = exp2f((ai + b4.w - c4.w) * LOG2E);
    *(float4*)(crow + lane * 4 + kk * 256) = r;
  }
}

extern "C" void kernel_launch(void* const* d_in, const int* in_sizes, int n_in,
                              void* d_out, int out_size, void* d_ws, size_t ws_size,
                              hipStream_t stream)
{
  const float* y = (const float*)d_in[0];   // setup_inputs order: y first
  const float* x = (const float*)d_in[1];

  float* out = (float*)d_out;

  // ws layout (union of both paths; ~8.3 MB)
  float* pm     = (float*)d_ws;                       // [NB][NCH][PP] = 1M floats
  float* ps     = pm + (size_t)NB * NCH * PP;         // 1M floats
  float* bg     = ps + (size_t)NB * NCH * PP;         // 16K floats
  float* errBlk = bg + NB * PP;                       // 1024 floats
  int*   doneF  = (int*)(errBlk + NBLK);              // 16 ints
  float* aF     = (float*)(doneF + 16);               // 16K (fallback a)
  float* bF     = aF + NB * PP;                       // 16K (fallback b)
  float* errR   = bF + NB * PP;                       // 16K (fallback err_rows)
  int*   doneA  = (int*)(errR + NB * PP);             // 16 (fallback doneArr)

  // --- capture-safe host-side queries: mirror the runtime's coop capacity check
  int dev = 0, numCU = 0, occ = 0;
  hipGetDevice(&dev);
  hipDeviceGetAttribute(&numCU, hipDeviceAttributeMultiprocessorCount, dev);
  hipOccupancyMaxActiveBlocksPerMultiprocessor(&occ, sinkhorn_fused, 256, 0);

  bool launched = false;
  if ((long)occ * (long)numCU >= (long)NBLK) {
    void* args[] = {(void*)&x, (void*)&y, (void*)&out, (void*)&pm, (void*)&ps,
                    (void*)&bg, (void*)&errBlk, (void*)&doneF};
    hipError_t e = hipLaunchCooperativeKernel(sinkhorn_fused, dim3(NBLK), dim3(256),
                                              args, 0, stream);
    launched = (e == hipSuccess);
  }

  if (!launched) {
    // proven round-2 path
    compute_c<<<NB * 16 * 8, 256, 0, stream>>>(x, y, out, aF, bF, doneA);
    for (int it = 0; it < MAX_ITER; ++it) {
      u_kernel <<<NB * PP / 4,   256, 0, stream>>>(out, aF, bF, errR, doneA, it);
      v_partial<<<NB * NCHUNK,   256, 0, stream>>>(out, aF, pm, ps, doneA, it);
      v_combine<<<NB * PP / 256, 256, 0, stream>>>(pm, ps, bF, errR, doneA, it);
    }
    pi_kernel<<<NB * PP / 4, 256, 0, stream>>>(out, aF, bF);
  }
}

// Round 5
// 417.788 us; speedup vs baseline: 1.3857x; 1.3857x over previous
//
#include <hip/hip_runtime.h>
#include <math.h>

#define NB 16
#define PP 1024
#define DD 64
#define MAX_ITER 10
#define RCH 16                 // rows per iter-block chunk
#define NCH (PP / RCH)         // 64 chunks per batch
#define NBLK (NB * NCH)        // 1024 iter blocks

constexpr float EPSV    = 0.1f;
constexpr float INV_EPS = 10.0f;
constexpr float LOG2E   = 1.44269504088896340736f;
constexpr float LOG_MU  = -6.93146156597137f;   // log(1/1024 + 1e-8)
constexpr float THRESHV = 0.1f;

// ---------------------------------------------------------------------------
// Cs[n][i][j] = |x_i - y_j|^2 / eps  (into d_out; later overwritten by pi)
// Grid 2048: n(16) x itile(16, 64 rows) x jtile(8, 128 cols). Proven round-2.
// ---------------------------------------------------------------------------
__global__ __launch_bounds__(256) void compute_c(
    const float* __restrict__ x, const float* __restrict__ y,
    float* __restrict__ Cs)
{
  const int bid = blockIdx.x;
  const int n   = bid >> 7;
  const int ib  = (bid >> 3) & 15;
  const int jb  = bid & 7;

  __shared__ float xs[64][68];
  __shared__ float ys[128][68];

  const float* xb = x + ((size_t)n * PP + ib * 64) * DD;
  const float* yb = y + ((size_t)n * PP + jb * 128) * DD;

  for (int t = threadIdx.x; t < 64 * 16; t += 256) {
    int r = t >> 4, d4 = (t & 15) * 4;
    float4 v = *(const float4*)(xb + r * DD + d4);
    xs[r][d4] = v.x; xs[r][d4 + 1] = v.y; xs[r][d4 + 2] = v.z; xs[r][d4 + 3] = v.w;
  }
  for (int t = threadIdx.x; t < 128 * 16; t += 256) {
    int r = t >> 4, d4 = (t & 15) * 4;
    float4 v = *(const float4*)(yb + (size_t)r * DD + d4);
    ys[r][d4] = v.x; ys[r][d4 + 1] = v.y; ys[r][d4 + 2] = v.z; ys[r][d4 + 3] = v.w;
  }
  __syncthreads();

  const int tx = threadIdx.x & 15;
  const int ty = threadIdx.x >> 4;
  const int i0 = ty * 4;

  float acc[4][8] = {};
  for (int d0 = 0; d0 < 64; d0 += 4) {
    float4 xv[4], yv[8];
    #pragma unroll
    for (int ii = 0; ii < 4; ++ii) xv[ii] = *(const float4*)&xs[i0 + ii][d0];
    #pragma unroll
    for (int jj = 0; jj < 8; ++jj) yv[jj] = *(const float4*)&ys[tx + 16 * jj][d0];
    #pragma unroll
    for (int ii = 0; ii < 4; ++ii) {
      #pragma unroll
      for (int jj = 0; jj < 8; ++jj) {
        float d;
        d = xv[ii].x - yv[jj].x; acc[ii][jj] = fmaf(d, d, acc[ii][jj]);
        d = xv[ii].y - yv[jj].y; acc[ii][jj] = fmaf(d, d, acc[ii][jj]);
        d = xv[ii].z - yv[jj].z; acc[ii][jj] = fmaf(d, d, acc[ii][jj]);
        d = xv[ii].w - yv[jj].w; acc[ii][jj] = fmaf(d, d, acc[ii][jj]);
      }
    }
  }

  float* outb = Cs + ((size_t)n * PP + ib * 64) * PP + jb * 128;
  #pragma unroll
  for (int ii = 0; ii < 4; ++ii)
    #pragma unroll
    for (int jj = 0; jj < 8; ++jj)
      outb[(size_t)(i0 + ii) * PP + tx + 16 * jj] = acc[ii][jj] * INV_EPS;
}

// ---------------------------------------------------------------------------
// Fused iteration: block = (n, rc) owns 16x1024 chunk of Cs; touches it once.
// Row phase: 16 threads/row, online (m,s) + in-wave shfl_xor merge -> a update.
// Col phase: thread's 4 cols, online (m,s) over the 16 rows (L2 re-read) -> partials.
// it==0: a_old=0, b=0 (no reads of aG/bG -> no init kernel, no stale state).
// ---------------------------------------------------------------------------
__global__ __launch_bounds__(256) void iter_fused(
    const float* __restrict__ Cs, float* __restrict__ aG, const float* __restrict__ bG,
    float* __restrict__ pm, float* __restrict__ ps, float* __restrict__ errBlk,
    const int* __restrict__ doneFlags, int it)
{
  if (it > 0 && doneFlags[it - 1]) return;   // frozen: a,b,partials untouched

  const int n   = blockIdx.x >> 6;
  const int rc  = blockIdx.x & (NCH - 1);
  const int tid = threadIdx.x;

  __shared__ float bb[PP];
  __shared__ float aArr[RCH];
  __shared__ float dsum[RCH];

  // stage b-chunk in LDS (zeros at it==0)
  if (it == 0) {
    *(float4*)&bb[tid * 4] = make_float4(0.f, 0.f, 0.f, 0.f);
  } else {
    *(float4*)&bb[tid * 4] = *(const float4*)(bG + n * PP + tid * 4);
  }
  __syncthreads();

  // ---- row phase: row r0 = tid>>4, col-group k = tid&15 (cols 4k+64j) ----
  const int r0 = tid >> 4;
  const int k  = tid & 15;
  const int row = n * PP + rc * RCH + r0;
  const float* crow = Cs + (size_t)row * PP;

  float m = -INFINITY, s = 0.f;
  #pragma unroll
  for (int j = 0; j < 16; ++j) {
    const int c = 4 * k + 64 * j;
    float4 c4 = *(const float4*)(crow + c);
    float4 b4 = *(const float4*)&bb[c];
    float t0 = b4.x - c4.x, t1 = b4.y - c4.y, t2 = b4.z - c4.z, t3 = b4.w - c4.w;
    float tmax = fmaxf(fmaxf(t0, t1), fmaxf(t2, t3));
    float mn = fmaxf(m, tmax);
    s = s * exp2f((m - mn) * LOG2E)
      + exp2f((t0 - mn) * LOG2E) + exp2f((t1 - mn) * LOG2E)
      + exp2f((t2 - mn) * LOG2E) + exp2f((t3 - mn) * LOG2E);
    m = mn;
  }
  // merge (m,s) across the 16 threads of this row (in-wave, symmetric -> identical)
  #pragma unroll
  for (int mask = 8; mask; mask >>= 1) {
    float om = __shfl_xor(m, mask);
    float os = __shfl_xor(s, mask);
    float mn = fmaxf(m, om);
    s = s * exp2f((m - mn) * LOG2E) + os * exp2f((om - mn) * LOG2E);
    m = mn;
  }
  if (k == 0) {
    float aOld = (it == 0) ? 0.f : aG[row];
    float an = LOG_MU - (m + logf(s));
    aG[row]  = an;
    aArr[r0] = an;
    dsum[r0] = fabsf(an - aOld);
  }
  __syncthreads();
  if (tid == 0) {
    float e = 0.f;
    #pragma unroll
    for (int r = 0; r < RCH; ++r) e += dsum[r];
    errBlk[blockIdx.x] = e;
  }

  // ---- col phase: thread owns cols c0..c0+3; 16-row online (m,s); L2 re-read ----
  const int c0 = tid * 4;
  const float* cb = Cs + ((size_t)(n * PP + rc * RCH)) * PP + c0;
  float m0 = -INFINITY, m1 = -INFINITY, m2 = -INFINITY, m3 = -INFINITY;
  float s0 = 0.f, s1 = 0.f, s2 = 0.f, s3 = 0.f;
  #pragma unroll
  for (int r = 0; r < RCH; ++r) {
    float ar = aArr[r];
    float4 c4 = *(const float4*)(cb + (size_t)r * PP);
    float t, mn;
    t = ar - c4.x; mn = fmaxf(m0, t); s0 = fmaf(s0, exp2f((m0-mn)*LOG2E), exp2f((t-mn)*LOG2E)); m0 = mn;
    t = ar - c4.y; mn = fmaxf(m1, t); s1 = fmaf(s1, exp2f((m1-mn)*LOG2E), exp2f((t-mn)*LOG2E)); m1 = mn;
    t = ar - c4.z; mn = fmaxf(m2, t); s2 = fmaf(s2, exp2f((m2-mn)*LOG2E), exp2f((t-mn)*LOG2E)); m2 = mn;
    t = ar - c4.w; mn = fmaxf(m3, t); s3 = fmaf(s3, exp2f((m3-mn)*LOG2E), exp2f((t-mn)*LOG2E)); m3 = mn;
  }
  size_t off = ((size_t)(n * NCH + rc)) * PP + c0;
  *(float4*)(pm + off) = make_float4(m0, m1, m2, m3);
  *(float4*)(ps + off) = make_float4(s0, s1, s2, s3);
}

// ---------------------------------------------------------------------------
// Combine partials -> b; block 0 reduces errBlk (fixed order) -> doneFlags[it].
// ---------------------------------------------------------------------------
__global__ __launch_bounds__(256) void v_combine(
    const float* __restrict__ pm, const float* __restrict__ ps,
    float* __restrict__ bG, const float* __restrict__ errBlk,
    int* __restrict__ doneFlags, int it)
{
  if (it > 0 && doneFlags[it - 1]) {
    if (blockIdx.x == 0 && threadIdx.x == 0) doneFlags[it] = 1;
    return;
  }
  const int col = blockIdx.x * 256 + threadIdx.x;   // 0..16383
  const int n = col >> 10, j = col & (PP - 1);
  const float* pmn = pm + (size_t)n * NCH * PP + j;
  const float* psn = ps + (size_t)n * NCH * PP + j;

  float m = -INFINITY, s = 0.f;
  #pragma unroll 8
  for (int c = 0; c < NCH; ++c) {
    float mc = pmn[(size_t)c * PP];
    float sc = psn[(size_t)c * PP];
    float mn = fmaxf(m, mc);
    s = fmaf(s, exp2f((m - mn) * LOG2E), sc * exp2f((mc - mn) * LOG2E));
    m = mn;
  }
  bG[col] = LOG_MU - (m + logf(s));

  if (blockIdx.x == 0) {
    __shared__ float red[4];
    float loc = 0.f;
    for (int t = threadIdx.x; t < NBLK; t += 256) loc += errBlk[t];
    #pragma unroll
    for (int off = 32; off > 0; off >>= 1) loc += __shfl_xor(loc, off);
    if ((threadIdx.x & 63) == 0) red[threadIdx.x >> 6] = loc;
    __syncthreads();
    if (threadIdx.x == 0) {
      float tot = red[0] + red[1] + red[2] + red[3];
      float err = tot * (EPSV / (float)NB);
      doneFlags[it] = (err < THRESHV) ? 1 : 0;
    }
  }
}

// ---------------------------------------------------------------------------
// pi = exp(a_i + b_j - Cs_ij), in place over Cs (d_out).
// ---------------------------------------------------------------------------
__global__ __launch_bounds__(256) void pi_kernel(
    float* __restrict__ Cs, const float* __restrict__ a, const float* __restrict__ b)
{
  const int lane = threadIdx.x & 63;
  const int row  = (blockIdx.x << 2) + (threadIdx.x >> 6);
  const int n    = row >> 10;
  const float ai = a[row];
  float* crow = Cs + (size_t)row * PP;
  const float* bn = b + n * PP;
  #pragma unroll
  for (int kk = 0; kk < 4; ++kk) {
    float4 c4 = *(const float4*)(crow + lane * 4 + kk * 256);
    float4 b4 = *(const float4*)(bn   + lane * 4 + kk * 256);
    float4 r;
    r.x = exp2f((ai + b4.x - c4.x) * LOG2E);
    r.y = exp2f((ai + b4.y - c4.y) * LOG2E);
    r.z = exp2f((ai + b4.z - c4.z) * LOG2E);
    r.w = exp2f((ai + b4.w - c4.w) * LOG2E);
    *(float4*)(crow + lane * 4 + kk * 256) = r;
  }
}

extern "C" void kernel_launch(void* const* d_in, const int* in_sizes, int n_in,
                              void* d_out, int out_size, void* d_ws, size_t ws_size,
                              hipStream_t stream)
{
  const float* y = (const float*)d_in[0];   // setup_inputs order: y first
  const float* x = (const float*)d_in[1];

  float* Cs      = (float*)d_out;                    // 16M floats (Cs, then pi in place)
  float* pm      = (float*)d_ws;                     // [NB][NCH][PP] = 1M floats
  float* ps      = pm + (size_t)NB * NCH * PP;       // 1M floats
  float* bGl     = ps + (size_t)NB * NCH * PP;       // 16K floats
  float* aGl     = bGl + NB * PP;                    // 16K floats
  float* errBlk  = aGl + NB * PP;                    // 1024 floats
  int*   doneFl  = (int*)(errBlk + NBLK);            // MAX_ITER ints

  compute_c<<<NB * 16 * 8, 256, 0, stream>>>(x, y, Cs);
  for (int it = 0; it < MAX_ITER; ++it) {
    iter_fused<<<NBLK, 256, 0, stream>>>(Cs, aGl, bGl, pm, ps, errBlk, doneFl, it);
    v_combine<<<NB * PP / 256, 256, 0, stream>>>(pm, ps, bGl, errBlk, doneFl, it);
  }
  pi_kernel<<<NB * PP / 4, 256, 0, stream>>>(Cs, aGl, bGl);
}

// Round 6
// 386.917 us; speedup vs baseline: 1.4962x; 1.0798x over previous
//
#include <hip/hip_runtime.h>
#include <math.h>

#define NB 16
#define PP 1024
#define DD 64
#define MAX_ITER 10
#define RCH 16                 // rows per iter-block chunk
#define NCH (PP / RCH)         // 64 chunks per batch
#define NBLK (NB * NCH)        // 1024 iter blocks

constexpr float EPSV    = 0.1f;
constexpr float INV_EPS = 10.0f;
constexpr float LOG2E   = 1.44269504088896340736f;
constexpr float LOG_MU  = -6.93146156597137f;   // log(1/1024 + 1e-8)
constexpr float THRESHV = 0.1f;

// ---------------------------------------------------------------------------
// Cs[n][i][j] = |x_i - y_j|^2 / eps  (into d_out; later overwritten by pi)
// 64x64 tiles, grid 4096 = 16 n x 16 itile x 16 jtile. 35 KB LDS -> 4 blk/CU.
// ---------------------------------------------------------------------------
__global__ __launch_bounds__(256) void compute_c(
    const float* __restrict__ x, const float* __restrict__ y,
    float* __restrict__ Cs)
{
  const int bid = blockIdx.x;
  const int n   = bid >> 8;
  const int ib  = (bid >> 4) & 15;
  const int jb  = bid & 15;

  __shared__ float xs[64][68];   // stride 68: float4-aligned, conflict-light
  __shared__ float ys[64][68];

  const float* xb = x + ((size_t)n * PP + ib * 64) * DD;
  const float* yb = y + ((size_t)n * PP + jb * 64) * DD;

  for (int t = threadIdx.x; t < 64 * 16; t += 256) {
    int r = t >> 4, d4 = (t & 15) * 4;
    float4 v = *(const float4*)(xb + r * DD + d4);
    xs[r][d4] = v.x; xs[r][d4 + 1] = v.y; xs[r][d4 + 2] = v.z; xs[r][d4 + 3] = v.w;
  }
  for (int t = threadIdx.x; t < 64 * 16; t += 256) {
    int r = t >> 4, d4 = (t & 15) * 4;
    float4 v = *(const float4*)(yb + (size_t)r * DD + d4);
    ys[r][d4] = v.x; ys[r][d4 + 1] = v.y; ys[r][d4 + 2] = v.z; ys[r][d4 + 3] = v.w;
  }
  __syncthreads();

  const int tx = threadIdx.x & 15;   // cols {tx, tx+16, tx+32, tx+48}
  const int ty = threadIdx.x >> 4;   // rows 4*ty .. 4*ty+3
  const int i0 = ty * 4;

  float acc[4][4] = {};
  for (int d0 = 0; d0 < 64; d0 += 4) {
    float4 xv[4], yv[4];
    #pragma unroll
    for (int ii = 0; ii < 4; ++ii) xv[ii] = *(const float4*)&xs[i0 + ii][d0];
    #pragma unroll
    for (int jj = 0; jj < 4; ++jj) yv[jj] = *(const float4*)&ys[tx + 16 * jj][d0];
    #pragma unroll
    for (int ii = 0; ii < 4; ++ii) {
      #pragma unroll
      for (int jj = 0; jj < 4; ++jj) {
        float d;
        d = xv[ii].x - yv[jj].x; acc[ii][jj] = fmaf(d, d, acc[ii][jj]);
        d = xv[ii].y - yv[jj].y; acc[ii][jj] = fmaf(d, d, acc[ii][jj]);
        d = xv[ii].z - yv[jj].z; acc[ii][jj] = fmaf(d, d, acc[ii][jj]);
        d = xv[ii].w - yv[jj].w; acc[ii][jj] = fmaf(d, d, acc[ii][jj]);
      }
    }
  }

  float* outb = Cs + ((size_t)n * PP + ib * 64) * PP + jb * 64;
  #pragma unroll
  for (int ii = 0; ii < 4; ++ii)
    #pragma unroll
    for (int jj = 0; jj < 4; ++jj)
      outb[(size_t)(i0 + ii) * PP + tx + 16 * jj] = acc[ii][jj] * INV_EPS;
}

// ---------------------------------------------------------------------------
// Fused iteration, two-pass phases for MLP.
// Row phase: thread (r0=tid>>4, k=tid&15) loads its 16 float4 of row r0 into
// regs (independent loads), tree-max, then exp-sum; shfl merge across the
// 16-lane row group. Col phase: two passes (fmax, then exp) over the 16-row
// chunk, re-read hits L1/L2. it==0: a_old=0, b=0 (no stale-ws reads).
// ---------------------------------------------------------------------------
__global__ __launch_bounds__(256, 4) void iter_fused(
    const float* __restrict__ Cs, float* __restrict__ aG, const float* __restrict__ bG,
    float* __restrict__ pm, float* __restrict__ ps, float* __restrict__ errBlk,
    const int* __restrict__ doneFlags, int it)
{
  if (it > 0 && doneFlags[it - 1]) return;   // frozen: a,b,partials untouched

  const int n   = blockIdx.x >> 6;
  const int rc  = blockIdx.x & (NCH - 1);
  const int tid = threadIdx.x;

  __shared__ float bb[PP];
  __shared__ float aArr[RCH];
  __shared__ float dsum[RCH];

  if (it == 0) {
    *(float4*)&bb[tid * 4] = make_float4(0.f, 0.f, 0.f, 0.f);
  } else {
    *(float4*)&bb[tid * 4] = *(const float4*)(bG + n * PP + tid * 4);
  }
  __syncthreads();

  // ---- row phase (two-pass in regs) ----
  const int r0  = tid >> 4;
  const int k   = tid & 15;
  const int row = n * PP + rc * RCH + r0;
  const float* crow = Cs + (size_t)row * PP + 4 * k;

  float4 tv[16];
  #pragma unroll
  for (int j = 0; j < 16; ++j) {
    float4 c4 = *(const float4*)(crow + 64 * j);
    float4 b4 = *(const float4*)&bb[4 * k + 64 * j];
    tv[j] = make_float4(b4.x - c4.x, b4.y - c4.y, b4.z - c4.z, b4.w - c4.w);
  }
  float m = -INFINITY;
  #pragma unroll
  for (int j = 0; j < 16; ++j)
    m = fmaxf(m, fmaxf(fmaxf(tv[j].x, tv[j].y), fmaxf(tv[j].z, tv[j].w)));
  #pragma unroll
  for (int mask = 8; mask; mask >>= 1) m = fmaxf(m, __shfl_xor(m, mask));

  float s = 0.f;
  #pragma unroll
  for (int j = 0; j < 16; ++j) {
    s += exp2f((tv[j].x - m) * LOG2E) + exp2f((tv[j].y - m) * LOG2E)
       + exp2f((tv[j].z - m) * LOG2E) + exp2f((tv[j].w - m) * LOG2E);
  }
  #pragma unroll
  for (int mask = 8; mask; mask >>= 1) s += __shfl_xor(s, mask);

  if (k == 0) {
    float aOld = (it == 0) ? 0.f : aG[row];
    float an = LOG_MU - (m + logf(s));
    aG[row]  = an;
    aArr[r0] = an;
    dsum[r0] = fabsf(an - aOld);
  }
  __syncthreads();
  if (tid == 0) {
    float e = 0.f;
    #pragma unroll
    for (int r = 0; r < RCH; ++r) e += dsum[r];
    errBlk[blockIdx.x] = e;
  }

  // ---- col phase (two-pass, chunk re-read from L1/L2) ----
  const int c0 = tid * 4;
  const float* cb = Cs + ((size_t)(n * PP + rc * RCH)) * PP + c0;

  float m0 = -INFINITY, m1 = -INFINITY, m2 = -INFINITY, m3 = -INFINITY;
  #pragma unroll
  for (int r = 0; r < RCH; ++r) {
    float ar = aArr[r];
    float4 c4 = *(const float4*)(cb + (size_t)r * PP);
    m0 = fmaxf(m0, ar - c4.x);
    m1 = fmaxf(m1, ar - c4.y);
    m2 = fmaxf(m2, ar - c4.z);
    m3 = fmaxf(m3, ar - c4.w);
  }
  float s0 = 0.f, s1 = 0.f, s2 = 0.f, s3 = 0.f;
  #pragma unroll
  for (int r = 0; r < RCH; ++r) {
    float ar = aArr[r];
    float4 c4 = *(const float4*)(cb + (size_t)r * PP);
    s0 += exp2f((ar - c4.x - m0) * LOG2E);
    s1 += exp2f((ar - c4.y - m1) * LOG2E);
    s2 += exp2f((ar - c4.z - m2) * LOG2E);
    s3 += exp2f((ar - c4.w - m3) * LOG2E);
  }
  size_t off = ((size_t)(n * NCH + rc)) * PP + c0;
  *(float4*)(pm + off) = make_float4(m0, m1, m2, m3);
  *(float4*)(ps + off) = make_float4(s0, s1, s2, s3);
}

// ---------------------------------------------------------------------------
// Combine partials -> b; block 0 reduces errBlk (fixed order) -> doneFlags[it].
// ---------------------------------------------------------------------------
__global__ __launch_bounds__(256) void v_combine(
    const float* __restrict__ pm, const float* __restrict__ ps,
    float* __restrict__ bG, const float* __restrict__ errBlk,
    int* __restrict__ doneFlags, int it)
{
  if (it > 0 && doneFlags[it - 1]) {
    if (blockIdx.x == 0 && threadIdx.x == 0) doneFlags[it] = 1;
    return;
  }
  const int col = blockIdx.x * 256 + threadIdx.x;   // 0..16383
  const int n = col >> 10, j = col & (PP - 1);
  const float* pmn = pm + (size_t)n * NCH * PP + j;
  const float* psn = ps + (size_t)n * NCH * PP + j;

  float m = -INFINITY, s = 0.f;
  #pragma unroll 8
  for (int c = 0; c < NCH; ++c) {
    float mc = pmn[(size_t)c * PP];
    float sc = psn[(size_t)c * PP];
    float mn = fmaxf(m, mc);
    s = fmaf(s, exp2f((m - mn) * LOG2E), sc * exp2f((mc - mn) * LOG2E));
    m = mn;
  }
  bG[col] = LOG_MU - (m + logf(s));

  if (blockIdx.x == 0) {
    __shared__ float red[4];
    float loc = 0.f;
    for (int t = threadIdx.x; t < NBLK; t += 256) loc += errBlk[t];
    #pragma unroll
    for (int off = 32; off > 0; off >>= 1) loc += __shfl_xor(loc, off);
    if ((threadIdx.x & 63) == 0) red[threadIdx.x >> 6] = loc;
    __syncthreads();
    if (threadIdx.x == 0) {
      float tot = red[0] + red[1] + red[2] + red[3];
      float err = tot * (EPSV / (float)NB);
      doneFlags[it] = (err < THRESHV) ? 1 : 0;
    }
  }
}

// ---------------------------------------------------------------------------
// pi = exp(a_i + b_j - Cs_ij), in place over Cs (d_out).
// ---------------------------------------------------------------------------
__global__ __launch_bounds__(256) void pi_kernel(
    float* __restrict__ Cs, const float* __restrict__ a, const float* __restrict__ b)
{
  const int lane = threadIdx.x & 63;
  const int row  = (blockIdx.x << 2) + (threadIdx.x >> 6);
  const int n    = row >> 10;
  const float ai = a[row];
  float* crow = Cs + (size_t)row * PP;
  const float* bn = b + n * PP;
  #pragma unroll
  for (int kk = 0; kk < 4; ++kk) {
    float4 c4 = *(const float4*)(crow + lane * 4 + kk * 256);
    float4 b4 = *(const float4*)(bn   + lane * 4 + kk * 256);
    float4 r;
    r.x = exp2f((ai + b4.x - c4.x) * LOG2E);
    r.y = exp2f((ai + b4.y - c4.y) * LOG2E);
    r.z = exp2f((ai + b4.z - c4.z) * LOG2E);
    r.w = exp2f((ai + b4.w - c4.w) * LOG2E);
    *(float4*)(crow + lane * 4 + kk * 256) = r;
  }
}

extern "C" void kernel_launch(void* const* d_in, const int* in_sizes, int n_in,
                              void* d_out, int out_size, void* d_ws, size_t ws_size,
                              hipStream_t stream)
{
  const float* y = (const float*)d_in[0];   // setup_inputs order: y first
  const float* x = (const float*)d_in[1];

  float* Cs      = (float*)d_out;                    // 16M floats (Cs, then pi in place)
  float* pm      = (float*)d_ws;                     // [NB][NCH][PP] = 1M floats
  float* ps      = pm + (size_t)NB * NCH * PP;       // 1M floats
  float* bGl     = ps + (size_t)NB * NCH * PP;       // 16K floats
  float* aGl     = bGl + NB * PP;                    // 16K floats
  float* errBlk  = aGl + NB * PP;                    // 1024 floats
  int*   doneFl  = (int*)(errBlk + NBLK);            // MAX_ITER ints

  compute_c<<<NB * 16 * 16, 256, 0, stream>>>(x, y, Cs);
  for (int it = 0; it < MAX_ITER; ++it) {
    iter_fused<<<NBLK, 256, 0, stream>>>(Cs, aGl, bGl, pm, ps, errBlk, doneFl, it);
    v_combine<<<NB * PP / 256, 256, 0, stream>>>(pm, ps, bGl, errBlk, doneFl, it);
  }
  pi_kernel<<<NB * PP / 4, 256, 0, stream>>>(Cs, aGl, bGl);
}

// Round 8
// 378.645 us; speedup vs baseline: 1.5289x; 1.0218x over previous
//
#include <hip/hip_runtime.h>
#include <math.h>

#define NB 16
#define PP 1024
#define DD 64
#define MAX_ITER 10
#define RCH 16                 // rows per iter-block chunk
#define NCH (PP / RCH)         // 64 chunks per batch
#define NBLK (NB * NCH)        // 1024 iter blocks

constexpr float EPSV    = 0.1f;
constexpr float SCALE_G = 20.0f;     // 2/eps
constexpr float LOG2E   = 1.44269504088896340736f;
constexpr float LOG_MU  = -6.93146156597137f;   // log(1/1024 + 1e-8)
constexpr float THRESHV = 0.1f;

typedef short bf16x8 __attribute__((ext_vector_type(8)));
typedef float f32x16 __attribute__((ext_vector_type(16)));

__device__ __forceinline__ unsigned short f2bf(float f) {
  unsigned int u = __float_as_uint(f);
  return (unsigned short)((u + 0x7FFFu + ((u >> 16) & 1u)) >> 16);   // RNE
}
__device__ __forceinline__ float bf2f(unsigned short h) {
  return __uint_as_float(((unsigned int)h) << 16);
}

// ---------------------------------------------------------------------------
// Prep: split x,y into bf16 hi/lo pairs + scaled row norms (10*|r|^2).
// Grid 1024: bid>>9 selects array (0=x,1=y); 32 rows/block; 8 threads/row.
// ---------------------------------------------------------------------------
__global__ __launch_bounds__(256) void prep_kernel(
    const float* __restrict__ x, const float* __restrict__ y,
    unsigned short* __restrict__ xh, unsigned short* __restrict__ xl,
    unsigned short* __restrict__ yh, unsigned short* __restrict__ yl,
    float* __restrict__ nxs, float* __restrict__ nys)
{
  const int sel = blockIdx.x >> 9;
  const int row = (blockIdx.x & 511) * 32 + (threadIdx.x >> 3);   // 0..16383
  const int q   = threadIdx.x & 7;

  const float* src = sel ? y : x;
  unsigned short* H = sel ? yh : xh;
  unsigned short* L = sel ? yl : xl;
  float* N          = sel ? nys : nxs;

  const float* p = src + (size_t)row * DD + q * 8;
  float4 v0 = *(const float4*)(p);
  float4 v1 = *(const float4*)(p + 4);

  float f[8] = {v0.x, v0.y, v0.z, v0.w, v1.x, v1.y, v1.z, v1.w};
  float nrm = 0.f;
  unsigned short hb[8], lb[8];
  #pragma unroll
  for (int k = 0; k < 8; ++k) {
    nrm = fmaf(f[k], f[k], nrm);
    unsigned short h = f2bf(f[k]);
    float res = f[k] - bf2f(h);
    hb[k] = h; lb[k] = f2bf(res);
  }
  nrm += __shfl_xor(nrm, 1);
  nrm += __shfl_xor(nrm, 2);
  nrm += __shfl_xor(nrm, 4);
  if (q == 0) N[row] = 10.0f * nrm;    // |r|^2 / eps

  uint4 ho, lo;
  ho.x = hb[0] | ((unsigned)hb[1] << 16); ho.y = hb[2] | ((unsigned)hb[3] << 16);
  ho.z = hb[4] | ((unsigned)hb[5] << 16); ho.w = hb[6] | ((unsigned)hb[7] << 16);
  lo.x = lb[0] | ((unsigned)lb[1] << 16); lo.y = lb[2] | ((unsigned)lb[3] << 16);
  lo.z = lb[4] | ((unsigned)lb[5] << 16); lo.w = lb[6] | ((unsigned)lb[7] << 16);
  *(uint4*)(H + (size_t)row * DD + q * 8) = ho;
  *(uint4*)(L + (size_t)row * DD + q * 8) = lo;
}

// ---------------------------------------------------------------------------
// Cs[n][i][j] = nxs_i + nys_j - 20*<x_i,y_j>  via split-bf16 MFMA (hh+hl+lh).
// Grid 4096 = 16 n x 16 itile x 16 jtile; 64x64 per block, 32x32 per wave.
// D layout (guide-verified): col=lane&31 (j), row=(reg&3)+8*(reg>>2)+4*(lane>>5) (i).
// ---------------------------------------------------------------------------
__global__ __launch_bounds__(256) void compute_c_mfma(
    const unsigned short* __restrict__ xh, const unsigned short* __restrict__ xl,
    const float* __restrict__ nxs,
    const unsigned short* __restrict__ yh, const unsigned short* __restrict__ yl,
    const float* __restrict__ nys,
    float* __restrict__ Cs)
{
  const int n   = blockIdx.x >> 8;
  const int ib  = (blockIdx.x >> 4) & 15;
  const int jb  = blockIdx.x & 15;
  const int tid = threadIdx.x;
  const int l   = tid & 63;
  const int w   = tid >> 6;
  const int ih  = w & 1, jh = w >> 1;

  __shared__ float nxv[64];
  if (tid < 64) nxv[tid] = nxs[n * PP + ib * 64 + tid];
  __syncthreads();

  const int jg  = n * PP + jb * 64 + 32 * jh + (l & 31);   // global y point (col)
  const float nyv = nys[jg];

  const int ko = 8 * (l >> 5);
  const size_t xrow = ((size_t)(n * PP + ib * 64 + 32 * ih + (l & 31))) * DD;
  const size_t yrow = ((size_t)jg) * DD;

  bf16x8 Xh0 = *(const bf16x8*)(xh + xrow + 0 * 16 + ko);
  bf16x8 Xh1 = *(const bf16x8*)(xh + xrow + 1 * 16 + ko);
  bf16x8 Xh2 = *(const bf16x8*)(xh + xrow + 2 * 16 + ko);
  bf16x8 Xh3 = *(const bf16x8*)(xh + xrow + 3 * 16 + ko);
  bf16x8 Xl0 = *(const bf16x8*)(xl + xrow + 0 * 16 + ko);
  bf16x8 Xl1 = *(const bf16x8*)(xl + xrow + 1 * 16 + ko);
  bf16x8 Xl2 = *(const bf16x8*)(xl + xrow + 2 * 16 + ko);
  bf16x8 Xl3 = *(const bf16x8*)(xl + xrow + 3 * 16 + ko);
  bf16x8 Yh0 = *(const bf16x8*)(yh + yrow + 0 * 16 + ko);
  bf16x8 Yh1 = *(const bf16x8*)(yh + yrow + 1 * 16 + ko);
  bf16x8 Yh2 = *(const bf16x8*)(yh + yrow + 2 * 16 + ko);
  bf16x8 Yh3 = *(const bf16x8*)(yh + yrow + 3 * 16 + ko);
  bf16x8 Yl0 = *(const bf16x8*)(yl + yrow + 0 * 16 + ko);
  bf16x8 Yl1 = *(const bf16x8*)(yl + yrow + 1 * 16 + ko);
  bf16x8 Yl2 = *(const bf16x8*)(yl + yrow + 2 * 16 + ko);
  bf16x8 Yl3 = *(const bf16x8*)(yl + yrow + 3 * 16 + ko);

  f32x16 acc;
  #pragma unroll
  for (int z = 0; z < 16; ++z) acc[z] = 0.f;
  acc = __builtin_amdgcn_mfma_f32_32x32x16_bf16(Xh0, Yh0, acc, 0, 0, 0);
  acc = __builtin_amdgcn_mfma_f32_32x32x16_bf16(Xh1, Yh1, acc, 0, 0, 0);
  acc = __builtin_amdgcn_mfma_f32_32x32x16_bf16(Xh2, Yh2, acc, 0, 0, 0);
  acc = __builtin_amdgcn_mfma_f32_32x32x16_bf16(Xh3, Yh3, acc, 0, 0, 0);
  acc = __builtin_amdgcn_mfma_f32_32x32x16_bf16(Xh0, Yl0, acc, 0, 0, 0);
  acc = __builtin_amdgcn_mfma_f32_32x32x16_bf16(Xh1, Yl1, acc, 0, 0, 0);
  acc = __builtin_amdgcn_mfma_f32_32x32x16_bf16(Xh2, Yl2, acc, 0, 0, 0);
  acc = __builtin_amdgcn_mfma_f32_32x32x16_bf16(Xh3, Yl3, acc, 0, 0, 0);
  acc = __builtin_amdgcn_mfma_f32_32x32x16_bf16(Xl0, Yh0, acc, 0, 0, 0);
  acc = __builtin_amdgcn_mfma_f32_32x32x16_bf16(Xl1, Yh1, acc, 0, 0, 0);
  acc = __builtin_amdgcn_mfma_f32_32x32x16_bf16(Xl2, Yh2, acc, 0, 0, 0);
  acc = __builtin_amdgcn_mfma_f32_32x32x16_bf16(Xl3, Yh3, acc, 0, 0, 0);

  const int irb  = 32 * ih + 4 * (l >> 5);
  const int jcol = jb * 64 + 32 * jh + (l & 31);
  #pragma unroll
  for (int r = 0; r < 16; ++r) {
    const int irel = irb + (r & 3) + 8 * (r >> 2);
    const size_t off = ((size_t)(n * PP + ib * 64 + irel)) * PP + jcol;
    Cs[off] = nxv[irel] + nyv - SCALE_G * acc[r];
  }
}

// ---------------------------------------------------------------------------
// Fused iteration (round-6, PROVEN): block = (n, rc) owns 16x1024 chunk of Cs.
// Row phase: two-pass in regs + shfl merge. Col phase: two-pass, L1/L2 re-read.
// it==0: a_old=0, b=0 (no stale-ws reads).
// ---------------------------------------------------------------------------
__global__ __launch_bounds__(256, 4) void iter_fused(
    const float* __restrict__ Cs, float* __restrict__ aG, const float* __restrict__ bG,
    float* __restrict__ pm, float* __restrict__ ps, float* __restrict__ errBlk,
    const int* __restrict__ doneFlags, int it)
{
  if (it > 0 && doneFlags[it - 1]) return;   // frozen: a,b,partials untouched

  const int n   = blockIdx.x >> 6;
  const int rc  = blockIdx.x & (NCH - 1);
  const int tid = threadIdx.x;

  __shared__ float bb[PP];
  __shared__ float aArr[RCH];
  __shared__ float dsum[RCH];

  if (it == 0) {
    *(float4*)&bb[tid * 4] = make_float4(0.f, 0.f, 0.f, 0.f);
  } else {
    *(float4*)&bb[tid * 4] = *(const float4*)(bG + n * PP + tid * 4);
  }
  __syncthreads();

  // ---- row phase (two-pass in regs) ----
  const int r0  = tid >> 4;
  const int k   = tid & 15;
  const int row = n * PP + rc * RCH + r0;
  const float* crow = Cs + (size_t)row * PP + 4 * k;

  float4 tv[16];
  #pragma unroll
  for (int j = 0; j < 16; ++j) {
    float4 c4 = *(const float4*)(crow + 64 * j);
    float4 b4 = *(const float4*)&bb[4 * k + 64 * j];
    tv[j] = make_float4(b4.x - c4.x, b4.y - c4.y, b4.z - c4.z, b4.w - c4.w);
  }
  float m = -INFINITY;
  #pragma unroll
  for (int j = 0; j < 16; ++j)
    m = fmaxf(m, fmaxf(fmaxf(tv[j].x, tv[j].y), fmaxf(tv[j].z, tv[j].w)));
  #pragma unroll
  for (int mask = 8; mask; mask >>= 1) m = fmaxf(m, __shfl_xor(m, mask));

  float s = 0.f;
  #pragma unroll
  for (int j = 0; j < 16; ++j) {
    s += exp2f((tv[j].x - m) * LOG2E) + exp2f((tv[j].y - m) * LOG2E)
       + exp2f((tv[j].z - m) * LOG2E) + exp2f((tv[j].w - m) * LOG2E);
  }
  #pragma unroll
  for (int mask = 8; mask; mask >>= 1) s += __shfl_xor(s, mask);

  if (k == 0) {
    float aOld = (it == 0) ? 0.f : aG[row];
    float an = LOG_MU - (m + logf(s));
    aG[row]  = an;
    aArr[r0] = an;
    dsum[r0] = fabsf(an - aOld);
  }
  __syncthreads();
  if (tid == 0) {
    float e = 0.f;
    #pragma unroll
    for (int r = 0; r < RCH; ++r) e += dsum[r];
    errBlk[blockIdx.x] = e;
  }

  // ---- col phase (two-pass, chunk re-read from L1/L2) ----
  const int c0 = tid * 4;
  const float* cb = Cs + ((size_t)(n * PP + rc * RCH)) * PP + c0;

  float m0 = -INFINITY, m1 = -INFINITY, m2 = -INFINITY, m3 = -INFINITY;
  #pragma unroll
  for (int r = 0; r < RCH; ++r) {
    float ar = aArr[r];
    float4 c4 = *(const float4*)(cb + (size_t)r * PP);
    m0 = fmaxf(m0, ar - c4.x);
    m1 = fmaxf(m1, ar - c4.y);
    m2 = fmaxf(m2, ar - c4.z);
    m3 = fmaxf(m3, ar - c4.w);
  }
  float s0 = 0.f, s1 = 0.f, s2 = 0.f, s3 = 0.f;
  #pragma unroll
  for (int r = 0; r < RCH; ++r) {
    float ar = aArr[r];
    float4 c4 = *(const float4*)(cb + (size_t)r * PP);
    s0 += exp2f((ar - c4.x - m0) * LOG2E);
    s1 += exp2f((ar - c4.y - m1) * LOG2E);
    s2 += exp2f((ar - c4.z - m2) * LOG2E);
    s3 += exp2f((ar - c4.w - m3) * LOG2E);
  }
  size_t off = ((size_t)(n * NCH + rc)) * PP + c0;
  *(float4*)(pm + off) = make_float4(m0, m1, m2, m3);
  *(float4*)(ps + off) = make_float4(s0, s1, s2, s3);
}

// ---------------------------------------------------------------------------
// Combine partials -> b; block 0 reduces errBlk (fixed order) -> doneFlags[it].
// ---------------------------------------------------------------------------
__global__ __launch_bounds__(256) void v_combine(
    const float* __restrict__ pm, const float* __restrict__ ps,
    float* __restrict__ bG, const float* __restrict__ errBlk,
    int* __restrict__ doneFlags, int it)
{
  if (it > 0 && doneFlags[it - 1]) {
    if (blockIdx.x == 0 && threadIdx.x == 0) doneFlags[it] = 1;
    return;
  }
  const int col = blockIdx.x * 256 + threadIdx.x;   // 0..16383
  const int n = col >> 10, j = col & (PP - 1);
  const float* pmn = pm + (size_t)n * NCH * PP + j;
  const float* psn = ps + (size_t)n * NCH * PP + j;

  float m = -INFINITY, s = 0.f;
  #pragma unroll 8
  for (int c = 0; c < NCH; ++c) {
    float mc = pmn[(size_t)c * PP];
    float sc = psn[(size_t)c * PP];
    float mn = fmaxf(m, mc);
    s = fmaf(s, exp2f((m - mn) * LOG2E), sc * exp2f((mc - mn) * LOG2E));
    m = mn;
  }
  bG[col] = LOG_MU - (m + logf(s));

  if (blockIdx.x == 0) {
    __shared__ float red[4];
    float loc = 0.f;
    for (int t = threadIdx.x; t < NBLK; t += 256) loc += errBlk[t];
    #pragma unroll
    for (int off = 32; off > 0; off >>= 1) loc += __shfl_xor(loc, off);
    if ((threadIdx.x & 63) == 0) red[threadIdx.x >> 6] = loc;
    __syncthreads();
    if (threadIdx.x == 0) {
      float tot = red[0] + red[1] + red[2] + red[3];
      float err = tot * (EPSV / (float)NB);
      doneFlags[it] = (err < THRESHV) ? 1 : 0;
    }
  }
}

// ---------------------------------------------------------------------------
// pi = exp(a_i + b_j - Cs_ij), in place over Cs (d_out).
// ---------------------------------------------------------------------------
__global__ __launch_bounds__(256) void pi_kernel(
    float* __restrict__ Cs, const float* __restrict__ a, const float* __restrict__ b)
{
  const int lane = threadIdx.x & 63;
  const int row  = (blockIdx.x << 2) + (threadIdx.x >> 6);
  const int n    = row >> 10;
  const float ai = a[row];
  float* crow = Cs + (size_t)row * PP;
  const float* bn = b + n * PP;
  #pragma unroll
  for (int kk = 0; kk < 4; ++kk) {
    float4 c4 = *(const float4*)(crow + lane * 4 + kk * 256);
    float4 b4 = *(const float4*)(bn   + lane * 4 + kk * 256);
    float4 r;
    r.x = exp2f((ai + b4.x - c4.x) * LOG2E);
    r.y = exp2f((ai + b4.y - c4.y) * LOG2E);
    r.z = exp2f((ai + b4.z - c4.z) * LOG2E);
    r.w = exp2f((ai + b4.w - c4.w) * LOG2E);
    *(float4*)(crow + lane * 4 + kk * 256) = r;
  }
}

extern "C" void kernel_launch(void* const* d_in, const int* in_sizes, int n_in,
                              void* d_out, int out_size, void* d_ws, size_t ws_size,
                              hipStream_t stream)
{
  const float* y = (const float*)d_in[0];   // setup_inputs order: y first
  const float* x = (const float*)d_in[1];

  float* Cs = (float*)d_out;                 // 16M floats (Cs, then pi in place)

  // ws layout: first 8 MB is a UNION — bf16 split arrays (used only before
  // the first iter_fused) alias pm/ps (used only from the first iter on).
  const size_t NE = (size_t)NB * PP * DD;    // 1,048,576 elems per split array
  unsigned short* xh = (unsigned short*)d_ws;
  unsigned short* xl = xh + NE;
  unsigned short* yh = xl + NE;
  unsigned short* yl = yh + NE;
  float* pm = (float*)d_ws;                  // [NB][NCH][PP] = 1M floats (4 MB)
  float* ps = pm + (size_t)NB * NCH * PP;    // 1M floats (4 MB)

  float* tail   = (float*)((char*)d_ws + 4 * NE * sizeof(unsigned short)); // +8 MB
  float* nxs    = tail;                      // 16K floats
  float* nys    = nxs + NB * PP;             // 16K
  float* aGl    = nys + NB * PP;             // 16K
  float* bGl    = aGl + NB * PP;             // 16K
  float* errBlk = bGl + NB * PP;             // 1024 floats
  int*   doneFl = (int*)(errBlk + NBLK);     // MAX_ITER ints

  prep_kernel<<<1024, 256, 0, stream>>>(x, y, xh, xl, yh, yl, nxs, nys);
  compute_c_mfma<<<4096, 256, 0, stream>>>(xh, xl, nxs, yh, yl, nys, Cs);
  for (int it = 0; it < MAX_ITER; ++it) {
    iter_fused<<<NBLK, 256, 0, stream>>>(Cs, aGl, bGl, pm, ps, errBlk, doneFl, it);
    v_combine<<<NB * PP / 256, 256, 0, stream>>>(pm, ps, bGl, errBlk, doneFl, it);
  }
  pi_kernel<<<NB * PP / 4, 256, 0, stream>>>(Cs, aGl, bGl);
}